// Round 12
// baseline (87.754 us; speedup 1.0000x reference)
//
#include <hip/hip_runtime.h>

typedef _Float16 h2 __attribute__((ext_vector_type(2)));
typedef float f4v __attribute__((ext_vector_type(4)));
typedef f4v f4u __attribute__((aligned(4)));   // 4B-aligned float4 (unaligned dwordx4)

#define N_EDGES 4000000
#define HID 8
#define NPT 2
#define TWO_LOG2E 2.8853900817779268f
#define LN_EPS 1e-5f

// ws float-slot layout (weights only, 184 words used)
#define O_GC0 0
#define O_BC0 8
#define O_GC1 16
#define O_BC1 24
#define O_GC2 32
#define O_BC2 40
#define O_B1  48
#define O_B2  56
#define O_B3  64    // 1 float
#define O_W1P 72    // 32 uint slots: packed h2 pairs, [j*4+q]
#define O_W2P 104   // 32
#define O_W3P 136   // 4
#define O_W0P 144   // 32 uint slots: per j, pairs {(w0,w1),(w2,0),(w3,w4),(w5,0)}
#define O_B0C 176   // 8 floats
#define NW    192   // LDS words staged

#if __has_builtin(__builtin_amdgcn_fdot2)
#define FDOT2(a, b, c) __builtin_amdgcn_fdot2((a), (b), (c), false)
#else
#define FDOT2(a, b, c) ((float)(a)[0] * (float)(b)[0] + ((float)(a)[1] * (float)(b)[1] + (c)))
#endif

// fold tanh affine into W (W' = -2*(W - rowmean)), refine rows in f16, pack;
// b' = b + colsum(W), centered over j.
__device__ void prep_hidden_layer(const float* __restrict__ W,
                                  const float* __restrict__ b,
                                  float* __restrict__ ws, uint* __restrict__ wsu,
                                  int wofs, int bofs) {
    float Wc[64];
    for (int k = 0; k < 8; ++k) {
        float rm = 0.f;
        for (int j = 0; j < 8; ++j) rm += W[k * 8 + j];
        rm *= 0.125f;
        for (int j = 0; j < 8; ++j) Wc[k * 8 + j] = -2.f * (W[k * 8 + j] - rm);
    }
    for (int k = 0; k < 8; ++k) {  // refine: f16-rounded rows keep ~zero mean
        float m = 0.f;
        for (int j = 0; j < 8; ++j) m += (float)(_Float16)Wc[k * 8 + j];
        m *= 0.125f;
        for (int j = 0; j < 8; ++j) Wc[k * 8 + j] -= m;
    }
    for (int j = 0; j < 8; ++j)
        for (int q = 0; q < 4; ++q) {
            h2 v;
            v[0] = (_Float16)Wc[(2 * q) * 8 + j];
            v[1] = (_Float16)Wc[(2 * q + 1) * 8 + j];
            wsu[wofs + j * 4 + q] = __builtin_bit_cast(uint, v);
        }
    float mb = 0.f, tot = 0.f;
    for (int j = 0; j < 8; ++j) mb += b[j];
    for (int i = 0; i < 64; ++i) tot += W[i];
    for (int j = 0; j < 8; ++j) {
        float cs = 0.f;
        for (int k = 0; k < 8; ++k) cs += W[k * 8 + j];
        ws[bofs + j] = b[j] + cs - mb * 0.125f - tot * 0.125f;
    }
}

__global__ void prep_kernel(
    const float* __restrict__ W0, const float* __restrict__ b0,
    const float* __restrict__ g0, const float* __restrict__ be0,
    const float* __restrict__ W1, const float* __restrict__ b1,
    const float* __restrict__ g1, const float* __restrict__ be1,
    const float* __restrict__ W2, const float* __restrict__ b2,
    const float* __restrict__ g2, const float* __restrict__ be2,
    const float* __restrict__ W3, const float* __restrict__ b3,
    float* __restrict__ ws)
{
    const int t = threadIdx.x;
    uint* wsu = reinterpret_cast<uint*>(ws);

    if (t == 0) {
        for (int j = 0; j < 8; ++j) {
            ws[O_GC0 + j] = g0[j] * TWO_LOG2E;  ws[O_BC0 + j] = be0[j] * TWO_LOG2E;
            ws[O_GC1 + j] = g1[j] * TWO_LOG2E;  ws[O_BC1 + j] = be1[j] * TWO_LOG2E;
            ws[O_GC2 + j] = g2[j] * TWO_LOG2E;  ws[O_BC2 + j] = be2[j] * TWO_LOG2E;
        }
    } else if (t == 1) {
        // W0: center rows over j, refine in f16, pack dot2 pairs; center b0
        float Wc[48];
        for (int k = 0; k < 6; ++k) {
            float rm = 0.f;
            for (int j = 0; j < 8; ++j) rm += W0[k * 8 + j];
            rm *= 0.125f;
            for (int j = 0; j < 8; ++j) Wc[k * 8 + j] = W0[k * 8 + j] - rm;
        }
        for (int k = 0; k < 6; ++k) {
            float m = 0.f;
            for (int j = 0; j < 8; ++j) m += (float)(_Float16)Wc[k * 8 + j];
            m *= 0.125f;
            for (int j = 0; j < 8; ++j) Wc[k * 8 + j] -= m;
        }
        for (int j = 0; j < 8; ++j) {
            h2 v;
            v[0] = (_Float16)Wc[0 * 8 + j]; v[1] = (_Float16)Wc[1 * 8 + j];
            wsu[O_W0P + j * 4 + 0] = __builtin_bit_cast(uint, v);
            v[0] = (_Float16)Wc[2 * 8 + j]; v[1] = (_Float16)0.f;
            wsu[O_W0P + j * 4 + 1] = __builtin_bit_cast(uint, v);
            v[0] = (_Float16)Wc[3 * 8 + j]; v[1] = (_Float16)Wc[4 * 8 + j];
            wsu[O_W0P + j * 4 + 2] = __builtin_bit_cast(uint, v);
            v[0] = (_Float16)Wc[5 * 8 + j]; v[1] = (_Float16)0.f;
            wsu[O_W0P + j * 4 + 3] = __builtin_bit_cast(uint, v);
        }
        float bm = 0.f;
        for (int j = 0; j < 8; ++j) bm += b0[j];
        bm *= 0.125f;
        for (int j = 0; j < 8; ++j) ws[O_B0C + j] = b0[j] - bm;
    } else if (t == 2) {
        prep_hidden_layer(W1, b1, ws, wsu, O_W1P, O_B1);
    } else if (t == 3) {
        prep_hidden_layer(W2, b2, ws, wsu, O_W2P, O_B2);
    } else if (t == 4) {
        float s = 0.f;
        for (int k = 0; k < 8; ++k) s += W3[k];
        ws[O_B3] = b3[0] + s;
        for (int q = 0; q < 4; ++q) {
            h2 v;
            v[0] = (_Float16)(-2.f * W3[2 * q]);
            v[1] = (_Float16)(-2.f * W3[2 * q + 1]);
            wsu[O_W3P + q] = __builtin_bit_cast(uint, v);
        }
    }
}

__global__ __launch_bounds__(256, 8) void edge_mlp_kernel(
    const float* __restrict__ x,
    const int*   __restrict__ ei,
    const float* __restrict__ ws,
    float* __restrict__ out)
{
    __shared__ float lw[NW];
    if (threadIdx.x < NW) lw[threadIdx.x] = ws[threadIdx.x];
    __syncthreads();
    const uint* lwu = reinterpret_cast<const uint*>(lw);

    const uint t = blockIdx.x * 256u + threadIdx.x;
    const uint base = t * NPT;
    if (base >= N_EDGES) return;

    // coalesced index loads (8 B each stream)
    const int2 sv = *reinterpret_cast<const int2*>(ei + base);
    const int2 dv = *reinterpret_cast<const int2*>(ei + N_EDGES + base);

    // random dwordx4 gathers (x[3n..3n+3], lane 3 unused)
    const f4u vs0 = *reinterpret_cast<const f4u*>(x + (uint)sv.x * 3u);
    const f4u vs1 = *reinterpret_cast<const f4u*>(x + (uint)sv.y * 3u);
    const f4u vd0 = *reinterpret_cast<const f4u*>(x + (uint)dv.x * 3u);
    const f4u vd1 = *reinterpret_cast<const f4u*>(x + (uint)dv.y * 3u);

    h2 s01[NPT], s2z[NPT], d01[NPT], d2z[NPT];
    s01[0] = __builtin_bit_cast(h2, __builtin_amdgcn_cvt_pkrtz(vs0[0], vs0[1]));
    s2z[0] = __builtin_bit_cast(h2, __builtin_amdgcn_cvt_pkrtz(vs0[2], 0.f));
    d01[0] = __builtin_bit_cast(h2, __builtin_amdgcn_cvt_pkrtz(vd0[0], vd0[1]));
    d2z[0] = __builtin_bit_cast(h2, __builtin_amdgcn_cvt_pkrtz(vd0[2], 0.f));
    s01[1] = __builtin_bit_cast(h2, __builtin_amdgcn_cvt_pkrtz(vs1[0], vs1[1]));
    s2z[1] = __builtin_bit_cast(h2, __builtin_amdgcn_cvt_pkrtz(vs1[2], 0.f));
    d01[1] = __builtin_bit_cast(h2, __builtin_amdgcn_cvt_pkrtz(vd1[0], vd1[1]));
    d2z[1] = __builtin_bit_cast(h2, __builtin_amdgcn_cvt_pkrtz(vd1[2], 0.f));

    // layer 0: 4 dot2 per (e,j) with packed centered W0 (weights from LDS)
    float z[NPT][HID];
#pragma unroll
    for (int j = 0; j < HID; ++j) {
        const h2 wj0 = __builtin_bit_cast(h2, lwu[O_W0P + j * 4 + 0]);
        const h2 wj1 = __builtin_bit_cast(h2, lwu[O_W0P + j * 4 + 1]);
        const h2 wj2 = __builtin_bit_cast(h2, lwu[O_W0P + j * 4 + 2]);
        const h2 wj3 = __builtin_bit_cast(h2, lwu[O_W0P + j * 4 + 3]);
        const float bb = lw[O_B0C + j];
#pragma unroll
        for (int e = 0; e < NPT; ++e) {
            float a = FDOT2(s01[e], wj0, bb);
            a = FDOT2(s2z[e], wj1, a);
            a = FDOT2(d01[e], wj2, a);
            z[e][j] = FDOT2(d2z[e], wj3, a);
        }
    }

    h2 p[NPT][4];
    const int gco[3] = {O_GC0, O_GC1, O_GC2};
    const int bco[3] = {O_BC0, O_BC1, O_BC2};
    const int wpo[2] = {O_W1P, O_W2P};
    const int bpo[2] = {O_B1, O_B2};

#pragma unroll
    for (int L = 0; L < 3; ++L) {
        // mean-free LN + folded-tanh sigmoid (pair-rcp), pack to f16
        float r[NPT];
#pragma unroll
        for (int e = 0; e < NPT; ++e) {
            float va = 0.f;
#pragma unroll
            for (int j = 0; j < HID; ++j) va = __builtin_fmaf(z[e][j], z[e][j], va);
            r[e] = __builtin_amdgcn_rsqf(__builtin_fmaf(va, 0.125f, LN_EPS));
        }
        const float* gc = lw + gco[L];
        const float* bc = lw + bco[L];
        float e1[NPT][HID];
#pragma unroll
        for (int j = 0; j < HID; ++j) {
            const float gcj = gc[j], bcj = bc[j];
#pragma unroll
            for (int e = 0; e < NPT; ++e) {
                const float y = __builtin_fmaf(z[e][j], r[e] * gcj, bcj);
                e1[e][j] = __builtin_amdgcn_exp2f(y) + 1.0f;
            }
        }
#pragma unroll
        for (int q = 0; q < 4; ++q)
#pragma unroll
            for (int e = 0; e < NPT; ++e) {
                const float a = e1[e][2 * q], b = e1[e][2 * q + 1];
                const float pr = __builtin_amdgcn_rcpf(a * b);
                p[e][q] = __builtin_bit_cast(h2,
                    __builtin_amdgcn_cvt_pkrtz(b * pr, a * pr));
            }
        if (L < 2) {
            const uint* wp = lwu + wpo[L];
            const float* bb = lw + bpo[L];
#pragma unroll
            for (int j = 0; j < HID; ++j) {
                const h2 w0 = __builtin_bit_cast(h2, wp[j * 4 + 0]);
                const h2 w1 = __builtin_bit_cast(h2, wp[j * 4 + 1]);
                const h2 w2 = __builtin_bit_cast(h2, wp[j * 4 + 2]);
                const h2 w3 = __builtin_bit_cast(h2, wp[j * 4 + 3]);
                const float bj = bb[j];
#pragma unroll
                for (int e = 0; e < NPT; ++e) {
                    float acc = FDOT2(p[e][0], w0, bj);
                    acc = FDOT2(p[e][1], w1, acc);
                    acc = FDOT2(p[e][2], w2, acc);
                    z[e][j] = FDOT2(p[e][3], w3, acc);
                }
            }
        }
    }

    // final layer: out = b3' + sum u_k * (-2 W3_k)
    const h2 w30 = __builtin_bit_cast(h2, lwu[O_W3P + 0]);
    const h2 w31 = __builtin_bit_cast(h2, lwu[O_W3P + 1]);
    const h2 w32 = __builtin_bit_cast(h2, lwu[O_W3P + 2]);
    const h2 w33 = __builtin_bit_cast(h2, lwu[O_W3P + 3]);
    const float bb3 = lw[O_B3];
    float o[NPT];
#pragma unroll
    for (int e = 0; e < NPT; ++e) {
        float acc = FDOT2(p[e][0], w30, bb3);
        acc = FDOT2(p[e][1], w31, acc);
        acc = FDOT2(p[e][2], w32, acc);
        o[e] = FDOT2(p[e][3], w33, acc);
    }

    *reinterpret_cast<float2*>(out + base) = make_float2(o[0], o[1]);
}

extern "C" void kernel_launch(void* const* d_in, const int* in_sizes, int n_in,
                              void* d_out, int out_size, void* d_ws, size_t ws_size,
                              hipStream_t stream) {
    const float* x   = (const float*)d_in[0];
    const int*   ei  = (const int*)d_in[1];
    const float* W0  = (const float*)d_in[2];
    const float* b0  = (const float*)d_in[3];
    const float* g0  = (const float*)d_in[4];
    const float* be0 = (const float*)d_in[5];
    const float* W1  = (const float*)d_in[6];
    const float* b1  = (const float*)d_in[7];
    const float* g1  = (const float*)d_in[8];
    const float* be1 = (const float*)d_in[9];
    const float* W2  = (const float*)d_in[10];
    const float* b2  = (const float*)d_in[11];
    const float* g2  = (const float*)d_in[12];
    const float* be2 = (const float*)d_in[13];
    const float* W3  = (const float*)d_in[14];
    const float* b3  = (const float*)d_in[15];
    float* out = (float*)d_out;
    float* ws  = (float*)d_ws;

    prep_kernel<<<1, 64, 0, stream>>>(W0, b0, g0, be0, W1, b1, g1, be1,
                                      W2, b2, g2, be2, W3, b3, ws);

    const int nthreads = N_EDGES / NPT;            // 2,000,000
    const int blocks = (nthreads + 255) / 256;     // 7813
    edge_mlp_kernel<<<blocks, 256, 0, stream>>>(x, ei, ws, out);
}

// Round 13
// 54.647 us; speedup vs baseline: 1.6058x; 1.6058x over previous
//
#include <hip/hip_runtime.h>

typedef _Float16 h2 __attribute__((ext_vector_type(2)));

#define N_EDGES 4000000
#define HID 8
#define NPT 4
#define TWO_LOG2E 2.8853900817779268f
#define LN_EPS 1e-5f

// ws float-slot layout (weights only, ~200 floats)
#define O_GC0 0
#define O_BC0 8
#define O_GC1 16
#define O_BC1 24
#define O_GC2 32
#define O_BC2 40
#define O_B1  48
#define O_B2  56
#define O_B3  64    // 1 float
#define O_W1P 72    // 32 uint slots: packed h2 pairs, [j*4+q]
#define O_W2P 104   // 32
#define O_W3P 136   // 4
#define O_W0C 144   // 48 floats: col-centered W0
#define O_B0C 192   // 8 floats

#if __has_builtin(__builtin_amdgcn_fdot2)
#define FDOT2(a, b, c) __builtin_amdgcn_fdot2((a), (b), (c), false)
#else
#define FDOT2(a, b, c) ((float)(a)[0] * (float)(b)[0] + ((float)(a)[1] * (float)(b)[1] + (c)))
#endif

__global__ void prep_kernel(
    const float* __restrict__ W0, const float* __restrict__ b0,
    const float* __restrict__ g0, const float* __restrict__ be0,
    const float* __restrict__ W1, const float* __restrict__ b1,
    const float* __restrict__ g1, const float* __restrict__ be1,
    const float* __restrict__ W2, const float* __restrict__ b2,
    const float* __restrict__ g2, const float* __restrict__ be2,
    const float* __restrict__ W3, const float* __restrict__ b3,
    float* __restrict__ ws)
{
    if (threadIdx.x != 0) return;
    uint* wsu = reinterpret_cast<uint*>(ws);
    for (int j = 0; j < 8; ++j) {
        ws[O_GC0 + j] = g0[j] * TWO_LOG2E;  ws[O_BC0 + j] = be0[j] * TWO_LOG2E;
        ws[O_GC1 + j] = g1[j] * TWO_LOG2E;  ws[O_BC1 + j] = be1[j] * TWO_LOG2E;
        ws[O_GC2 + j] = g2[j] * TWO_LOG2E;  ws[O_BC2 + j] = be2[j] * TWO_LOG2E;
    }
    // W0: center each row's 8 outputs (mean over j) so LN mean == 0; center b0
    {
        float bm = 0.f;
        for (int j = 0; j < 8; ++j) bm += b0[j];
        bm *= 0.125f;
        for (int j = 0; j < 8; ++j) ws[O_B0C + j] = b0[j] - bm;
        for (int k = 0; k < 6; ++k) {
            float rm = 0.f;
            for (int j = 0; j < 8; ++j) rm += W0[k * 8 + j];
            rm *= 0.125f;
            for (int j = 0; j < 8; ++j) ws[O_W0C + k * 8 + j] = W0[k * 8 + j] - rm;
        }
    }
    // W1 / W2: fold tanh affine (h = 1-2u -> W' = -2W, b' = b + colsum(W)),
    // center rows over j, refine in f16, pack as h2 pairs
    const float* Ws[2] = {W1, W2};
    const float* bs[2] = {b1, b2};
    const int    wo[2] = {O_W1P, O_W2P};
    const int    bo[2] = {O_B1, O_B2};
    for (int L = 0; L < 2; ++L) {
        const float* W = Ws[L];
        float Wc[64];
        for (int k = 0; k < 8; ++k) {
            float rm = 0.f;
            for (int j = 0; j < 8; ++j) rm += W[k * 8 + j];
            rm *= 0.125f;
            for (int j = 0; j < 8; ++j) Wc[k * 8 + j] = -2.f * (W[k * 8 + j] - rm);
        }
        for (int k = 0; k < 8; ++k) {  // refine: f16-rounded rows keep ~zero mean
            float m = 0.f;
            for (int j = 0; j < 8; ++j) m += (float)(_Float16)Wc[k * 8 + j];
            m *= 0.125f;
            for (int j = 0; j < 8; ++j) Wc[k * 8 + j] -= m;
        }
        for (int j = 0; j < 8; ++j)
            for (int q = 0; q < 4; ++q) {
                h2 v;
                v[0] = (_Float16)Wc[(2 * q) * 8 + j];
                v[1] = (_Float16)Wc[(2 * q + 1) * 8 + j];
                wsu[wo[L] + j * 4 + q] = __builtin_bit_cast(uint, v);
            }
        float mb = 0.f, tot = 0.f;
        for (int j = 0; j < 8; ++j) mb += bs[L][j];
        for (int i = 0; i < 64; ++i) tot += W[i];
        for (int j = 0; j < 8; ++j) {
            float cs = 0.f;
            for (int k = 0; k < 8; ++k) cs += W[k * 8 + j];
            ws[bo[L] + j] = bs[L][j] + cs - mb * 0.125f - tot * 0.125f;
        }
    }
    // W3: -2*W3 packed; b3' = b3 + sum(W3)
    {
        float s = 0.f;
        for (int k = 0; k < 8; ++k) s += W3[k];
        ws[O_B3] = b3[0] + s;
        for (int q = 0; q < 4; ++q) {
            h2 v;
            v[0] = (_Float16)(-2.f * W3[2 * q]);
            v[1] = (_Float16)(-2.f * W3[2 * q + 1]);
            wsu[O_W3P + q] = __builtin_bit_cast(uint, v);
        }
    }
}

// Mean-free LN + folded-tanh sigmoid u = 1/(1+exp2(y)); pair-rcp halves rcp
// count; outputs packed f16 pairs for dot2.
template<int N>
__device__ __forceinline__ void ln_pack(const float (&z)[N][HID],
                                        const float* __restrict__ gc,
                                        const float* __restrict__ bc,
                                        h2 (&p)[N][4]) {
    float r[N];
#pragma unroll
    for (int e = 0; e < N; ++e) {
        float va = 0.f;
#pragma unroll
        for (int j = 0; j < HID; ++j) va = __builtin_fmaf(z[e][j], z[e][j], va);
        r[e] = __builtin_amdgcn_rsqf(__builtin_fmaf(va, 0.125f, LN_EPS));
    }
    float e1[N][HID];
#pragma unroll
    for (int j = 0; j < HID; ++j) {
        const float gcj = gc[j], bcj = bc[j];
#pragma unroll
        for (int e = 0; e < N; ++e) {
            const float y = __builtin_fmaf(z[e][j], r[e] * gcj, bcj);
            e1[e][j] = __builtin_amdgcn_exp2f(y) + 1.0f;
        }
    }
#pragma unroll
    for (int q = 0; q < 4; ++q)
#pragma unroll
        for (int e = 0; e < N; ++e) {
            const float a = e1[e][2 * q], b = e1[e][2 * q + 1];
            const float pr = __builtin_amdgcn_rcpf(a * b);
            p[e][q] = __builtin_bit_cast(h2,
                __builtin_amdgcn_cvt_pkrtz(b * pr, a * pr));
        }
}

template<int N>
__device__ __forceinline__ void lin8_dot(const h2 (&p)[N][4],
                                         const uint* __restrict__ wp,
                                         const float* __restrict__ b,
                                         float (&zo)[N][HID]) {
#pragma unroll
    for (int j = 0; j < HID; ++j) {
        const float bj = b[j];
        const h2 w0 = __builtin_bit_cast(h2, wp[j * 4 + 0]);
        const h2 w1 = __builtin_bit_cast(h2, wp[j * 4 + 1]);
        const h2 w2 = __builtin_bit_cast(h2, wp[j * 4 + 2]);
        const h2 w3 = __builtin_bit_cast(h2, wp[j * 4 + 3]);
#pragma unroll
        for (int e = 0; e < N; ++e) {
            float acc = FDOT2(p[e][0], w0, bj);
            acc = FDOT2(p[e][1], w1, acc);
            acc = FDOT2(p[e][2], w2, acc);
            zo[e][j] = FDOT2(p[e][3], w3, acc);
        }
    }
}

__global__ __launch_bounds__(256) void edge_mlp_kernel(
    const float* __restrict__ x,
    const int*   __restrict__ ei,
    const float* __restrict__ ws,
    float* __restrict__ out)
{
    const int t = blockIdx.x * blockDim.x + threadIdx.x;
    const int base = t * NPT;
    if (base >= N_EDGES) return;

    const uint* wsu = reinterpret_cast<const uint*>(ws);
    const int4 sv = *reinterpret_cast<const int4*>(ei + base);
    const int4 dv = *reinterpret_cast<const int4*>(ei + N_EDGES + base);
    const int si[NPT] = {sv.x, sv.y, sv.z, sv.w};
    const int di[NPT] = {dv.x, dv.y, dv.z, dv.w};

    float xs[NPT][3], xd[NPT][3];
#pragma unroll
    for (int e = 0; e < NPT; ++e) {
#pragma unroll
        for (int c = 0; c < 3; ++c) {
            xs[e][c] = x[si[e] * 3 + c];
            xd[e][c] = x[di[e] * 3 + c];
        }
    }

    // layer 0 (centered f32 weights)
    float z[NPT][HID];
#pragma unroll
    for (int j = 0; j < HID; ++j) {
        const float w0 = ws[O_W0C + 0 * 8 + j], w1 = ws[O_W0C + 1 * 8 + j],
                    w2 = ws[O_W0C + 2 * 8 + j], w3 = ws[O_W0C + 3 * 8 + j],
                    w4 = ws[O_W0C + 4 * 8 + j], w5 = ws[O_W0C + 5 * 8 + j];
        const float bb = ws[O_B0C + j];
#pragma unroll
        for (int e = 0; e < NPT; ++e) {
            float a = __builtin_fmaf(xs[e][0], w0, bb);
            a = __builtin_fmaf(xs[e][1], w1, a);
            a = __builtin_fmaf(xs[e][2], w2, a);
            a = __builtin_fmaf(xd[e][0], w3, a);
            a = __builtin_fmaf(xd[e][1], w4, a);
            z[e][j] = __builtin_fmaf(xd[e][2], w5, a);
        }
    }

    h2 p[NPT][4];
    ln_pack<NPT>(z, ws + O_GC0, ws + O_BC0, p);
    lin8_dot<NPT>(p, wsu + O_W1P, ws + O_B1, z);
    ln_pack<NPT>(z, ws + O_GC1, ws + O_BC1, p);
    lin8_dot<NPT>(p, wsu + O_W2P, ws + O_B2, z);
    ln_pack<NPT>(z, ws + O_GC2, ws + O_BC2, p);

    // final layer: out = b3' + sum u_k * (-2 W3_k)
    const h2 w30 = __builtin_bit_cast(h2, wsu[O_W3P + 0]);
    const h2 w31 = __builtin_bit_cast(h2, wsu[O_W3P + 1]);
    const h2 w32 = __builtin_bit_cast(h2, wsu[O_W3P + 2]);
    const h2 w33 = __builtin_bit_cast(h2, wsu[O_W3P + 3]);
    const float bb3 = ws[O_B3];
    float o[NPT];
#pragma unroll
    for (int e = 0; e < NPT; ++e) {
        float acc = FDOT2(p[e][0], w30, bb3);
        acc = FDOT2(p[e][1], w31, acc);
        acc = FDOT2(p[e][2], w32, acc);
        o[e] = FDOT2(p[e][3], w33, acc);
    }

    *reinterpret_cast<float4*>(out + base) = make_float4(o[0], o[1], o[2], o[3]);
}

extern "C" void kernel_launch(void* const* d_in, const int* in_sizes, int n_in,
                              void* d_out, int out_size, void* d_ws, size_t ws_size,
                              hipStream_t stream) {
    const float* x   = (const float*)d_in[0];
    const int*   ei  = (const int*)d_in[1];
    const float* W0  = (const float*)d_in[2];
    const float* b0  = (const float*)d_in[3];
    const float* g0  = (const float*)d_in[4];
    const float* be0 = (const float*)d_in[5];
    const float* W1  = (const float*)d_in[6];
    const float* b1  = (const float*)d_in[7];
    const float* g1  = (const float*)d_in[8];
    const float* be1 = (const float*)d_in[9];
    const float* W2  = (const float*)d_in[10];
    const float* b2  = (const float*)d_in[11];
    const float* g2  = (const float*)d_in[12];
    const float* be2 = (const float*)d_in[13];
    const float* W3  = (const float*)d_in[14];
    const float* b3  = (const float*)d_in[15];
    float* out = (float*)d_out;
    float* ws  = (float*)d_ws;

    prep_kernel<<<1, 64, 0, stream>>>(W0, b0, g0, be0, W1, b1, g1, be1,
                                      W2, b2, g2, be2, W3, b3, ws);

    const int nthreads = N_EDGES / NPT;          // 1,000,000
    const int blocks = (nthreads + 255) / 256;   // 3907
    edge_mlp_kernel<<<blocks, 256, 0, stream>>>(x, ei, ws, out);
}